// Round 4
// baseline (15292.500 us; speedup 1.0000x reference)
//
#include <hip/hip_runtime.h>

// CharRNN: 3-layer shared-weight LSTM (H=65) over T=4096, B=50, + dense head.
//
// Kernel 1 (recurrent): one workgroup per sequence, layers wavefront-pipelined
//   (round r: layer l does t=r-l). Thread owns ONE W-column or ONE U-column and
//   computes it for ALL 3 layers (shared weights).
//
// Round-4 change vs round-3: weights live in 17 NAMED float4 registers
// (w00..w16, padded to 68) + 9 named scalars for the leftover columns.
// R1-R3 all showed VGPR_Count=64: the compiler never promoted the indexed
// float wgt[65] array — it sat in scratch, and the kernel was latency-bound
// on private-segment reloads (~400KB/CU/round). Named vars force promotion.

#define HH    65
#define G4    260
#define TT    4096
#define NB    50
#define BLOCK 512
#define DROWS 64

__device__ __forceinline__ float sigm(float x)  { return 1.0f / (1.0f + __expf(-x)); }
__device__ __forceinline__ float tanha(float x) { float e = __expf(2.0f * x); return 1.0f - 2.0f / (e + 1.0f); }

__global__ void __launch_bounds__(BLOCK, 1)
charrnn_rec(const float* __restrict__ x, const float* __restrict__ W,
            const float* __restrict__ U, const float* __restrict__ bv,
            float* __restrict__ out)
{
    __shared__ __align__(16) float s_hin[3][68];   // input to layer l this round (row0 = x(t)); [65..67]=0
    __shared__ __align__(16) float s_hrec[3][68];  // recurrent h per layer; [65..67]=0
    __shared__ float s_crec[3][HH];
    __shared__ float s_zW[3][G4];                  // hin-side partial pre-activations
    __shared__ float s_zU[3][G4];                  // hrec-side partials (cols 0..251)
    __shared__ float s_zUe[3][8][8];               // hrec-side partials, cols 252..259, 8 k-chunks

    const int bat  = blockIdx.x;
    const int tid  = threadIdx.x;
    const int lane = tid & 63;
    const int wv   = tid >> 6;
    const float* xb   = x   + (size_t)bat * TT * HH;
    float*       outb = out + (size_t)bat * TT * HH;

    for (int i = tid; i < 3 * 68; i += BLOCK) { (&s_hin[0][0])[i] = 0.0f; (&s_hrec[0][0])[i] = 0.0f; }
    for (int i = tid; i < 3 * HH; i += BLOCK) (&s_crec[0][0])[i] = 0.0f;

    // ---- main slot: W-column (tid<260) or U-column (260<=tid<512 -> cols 0..251) ----
    const bool isW = (tid < G4);
    const int  col = isW ? tid : tid - G4;
    const float* wsrc = isW ? W : U;
    const float bias  = isW ? bv[col] : 0.0f;

    // 65 weights (padded to 68) in NAMED float4 registers — never indexed.
    float4 w00, w01, w02, w03, w04, w05, w06, w07,
           w08, w09, w10, w11, w12, w13, w14, w15, w16;
#define WINIT(v, k0)                                                          \
    do {                                                                      \
        v.x = wsrc[(k0 + 0) * G4 + col];                                      \
        v.y = ((k0) + 1 < HH) ? wsrc[((k0) + 1) * G4 + col] : 0.0f;           \
        v.z = ((k0) + 2 < HH) ? wsrc[((k0) + 2) * G4 + col] : 0.0f;           \
        v.w = ((k0) + 3 < HH) ? wsrc[((k0) + 3) * G4 + col] : 0.0f;           \
    } while (0)
    WINIT(w00, 0);  WINIT(w01, 4);  WINIT(w02, 8);  WINIT(w03, 12);
    WINIT(w04, 16); WINIT(w05, 20); WINIT(w06, 24); WINIT(w07, 28);
    WINIT(w08, 32); WINIT(w09, 36); WINIT(w10, 40); WINIT(w11, 44);
    WINIT(w12, 48); WINIT(w13, 52); WINIT(w14, 56); WINIT(w15, 60);
    WINIT(w16, 64);
#undef WINIT

    // ---- leftover U-columns 252..259: k-chunk wv on lanes 56..63 of each wave ----
    const bool isL = (lane >= 56);
    const int  lc  = lane - 56;                        // col 252+lc
    const int  kst = (wv == 0) ? 0 : (9 + 8 * (wv - 1));
    const int  kln = (wv == 0) ? 9 : 8;
    float e0, e1, e2, e3, e4, e5, e6, e7, e8;
#define EINIT(i, v) v = (isL && (i) < kln) ? U[(kst + (i)) * G4 + (252 + lc)] : 0.0f
    EINIT(0, e0); EINIT(1, e1); EINIT(2, e2); EINIT(3, e3); EINIT(4, e4);
    EINIT(5, e5); EINIT(6, e6); EINIT(7, e7); EINIT(8, e8);
#undef EINIT

    // ---- x prefetch role: lanes 40..47 of each wave + tid 48 ----
    const bool isP  = (lane >= 40 && lane < 48) || (tid == 48);
    const int  pidx = (tid == 48) ? 64 : (wv * 8 + (lane - 40));
    float cur = 0.0f, nxt = 0.0f;
    if (isP) {
        s_hin[0][pidx] = xb[pidx];      // x(0)
        cur = xb[HH + pidx];            // x(1)
    }
    __syncthreads();

    for (int r = 0; r < TT + 2; ++r) {
        // ---------------- Phase A: gate partial dot-products ----------------
#pragma unroll
        for (int l = 0; l < 3; ++l) {
            if ((unsigned)(r - l) < TT) {
                const float* sb = isW ? &s_hin[l][0] : &s_hrec[l][0];
                const float4* s4 = (const float4*)sb;
                float a0 = bias, a1 = 0.0f;
#define GSTEP(i, wv4)                                                         \
    {                                                                         \
        const float4 hv = s4[i];                                              \
        a0 = fmaf(hv.x, wv4.x, a0); a1 = fmaf(hv.y, wv4.y, a1);               \
        a0 = fmaf(hv.z, wv4.z, a0); a1 = fmaf(hv.w, wv4.w, a1);               \
    }
                GSTEP(0,  w00) GSTEP(1,  w01) GSTEP(2,  w02) GSTEP(3,  w03)
                GSTEP(4,  w04) GSTEP(5,  w05) GSTEP(6,  w06) GSTEP(7,  w07)
                GSTEP(8,  w08) GSTEP(9,  w09) GSTEP(10, w10) GSTEP(11, w11)
                GSTEP(12, w12) GSTEP(13, w13) GSTEP(14, w14) GSTEP(15, w15)
                GSTEP(16, w16)
#undef GSTEP
                const float a = a0 + a1;
                if (isW) s_zW[l][col] = a; else s_zU[l][col] = a;
            }
        }
        if (isL) {
#pragma unroll
            for (int l = 0; l < 3; ++l) {
                if ((unsigned)(r - l) < TT) {
                    const float* hr = &s_hrec[l][0];
                    float a = 0.0f;
                    a = fmaf(hr[kst + 0], e0, a); a = fmaf(hr[kst + 1], e1, a);
                    a = fmaf(hr[kst + 2], e2, a); a = fmaf(hr[kst + 3], e3, a);
                    a = fmaf(hr[kst + 4], e4, a); a = fmaf(hr[kst + 5], e5, a);
                    a = fmaf(hr[kst + 6], e6, a); a = fmaf(hr[kst + 7], e7, a);
                    a = fmaf(hr[kst + 8], e8, a);   // wv>0: e8==0; index<=65 is padded
                    s_zUe[l][wv][lc] = a;
                }
            }
        }
        if (isP) {  // issue x(r+2); latency hidden under gate FMAs
            const int tn = r + 2;
            nxt = (tn < TT) ? xb[(size_t)tn * HH + pidx] : 0.0f;
        }
        __syncthreads();

        // ---------------- Phase B: cell updates ----------------
        if (tid < 195) {
            const int cl = tid / 65, n = tid - cl * 65;
            const int t  = r - cl;
            if ((unsigned)t < TT) {
                const float zi = s_zW[cl][n]       + s_zU[cl][n];
                const float zf = s_zW[cl][65 + n]  + s_zU[cl][65 + n];
                const float zg = s_zW[cl][130 + n] + s_zU[cl][130 + n];
                float zo = s_zW[cl][195 + n];
                if (n < 57) {
                    zo += s_zU[cl][195 + n];
                } else {
                    float a = 0.0f;
#pragma unroll
                    for (int w8 = 0; w8 < 8; ++w8) a += s_zUe[cl][w8][n - 57];
                    zo += a;
                }
                const float ig = sigm(zi), fg = sigm(zf), gg = tanha(zg), og = sigm(zo);
                const float c = fmaf(fg, s_crec[cl][n], ig * gg);
                const float h = og * tanha(c);
                s_crec[cl][n] = c;
                s_hrec[cl][n] = h;
                if (cl < 2) s_hin[cl + 1][n] = h;
                else        outb[(size_t)t * HH + n] = h;   // stream h2 to out
            }
        }
        if (isP) {
            if (r + 1 < TT) s_hin[0][pidx] = cur;
            cur = nxt;
        }
        __syncthreads();
    }
}

// ---- kernel 2: in-place dense head over d_out: y = h2 @ Wd + bd ----
__global__ void __launch_bounds__(256, 1)
dense_head(float* __restrict__ io, const float* __restrict__ Wd, const float* __restrict__ bd)
{
    __shared__ __align__(16) float s_h[DROWS][68];
    __shared__ float s_wd[HH][HH];
    __shared__ float s_bd[HH];

    const int tid = threadIdx.x;
    float* base = io + (size_t)blockIdx.x * DROWS * HH;

    for (int i = tid; i < DROWS * HH; i += 256) {
        const int row = i / HH, k = i - row * HH;
        s_h[row][k] = base[i];
    }
    for (int i = tid; i < HH * HH; i += 256) (&s_wd[0][0])[i] = Wd[i];
    if (tid < HH) s_bd[tid] = bd[tid];
    __syncthreads();

    for (int u = tid; u < DROWS * HH; u += 256) {
        const int row = u / HH, c = u - row * HH;
        const float4* hp = (const float4*)&s_h[row][0];
        float acc = s_bd[c];
#pragma unroll
        for (int k4 = 0; k4 < 16; ++k4) {
            const float4 hv = hp[k4];
            acc = fmaf(hv.x, s_wd[4 * k4 + 0][c], acc);
            acc = fmaf(hv.y, s_wd[4 * k4 + 1][c], acc);
            acc = fmaf(hv.z, s_wd[4 * k4 + 2][c], acc);
            acc = fmaf(hv.w, s_wd[4 * k4 + 3][c], acc);
        }
        acc = fmaf(s_h[row][64], s_wd[64][c], acc);
        base[u] = acc;   // safe: all reads come from LDS copies
    }
}

extern "C" void kernel_launch(void* const* d_in, const int* in_sizes, int n_in,
                              void* d_out, int out_size, void* d_ws, size_t ws_size,
                              hipStream_t stream)
{
    const float* x  = (const float*)d_in[0];
    const float* W  = (const float*)d_in[1];
    const float* U  = (const float*)d_in[2];
    const float* bv = (const float*)d_in[3];
    const float* Wd = (const float*)d_in[4];
    const float* bd = (const float*)d_in[5];
    float* out = (float*)d_out;

    hipLaunchKernelGGL(charrnn_rec, dim3(NB), dim3(BLOCK), 0, stream, x, W, U, bv, out);
    hipLaunchKernelGGL(dense_head, dim3(NB * TT / DROWS), dim3(256), 0, stream, out, Wd, bd);
}

// Round 5
// 13166.922 us; speedup vs baseline: 1.1614x; 1.1614x over previous
//
#include <hip/hip_runtime.h>

// CharRNN: 3-layer shared-weight LSTM (H=65) over T=4096, B=50, + dense head.
//
// Kernel 1 (recurrent): one workgroup per sequence, layers wavefront-pipelined
//   (round r: layer l does t=r-l). Thread owns TWO gate columns (W-side or
//   U-side) and computes them for ALL 3 layers — the LDS h-broadcast read is
//   shared across the thread's two columns (204 ds_read_b128/CU/round vs 408).
//
// Round-5 changes vs round-4:
//   * block 512 -> 256 (4 waves = exactly 1 wave/EU)
//   * __attribute__((amdgpu_waves_per_eu(1,1))): R2-R4 all reported
//     VGPR_Count=64 = 512/8waves — the allocator was TARGETING occupancy and
//     spilling the weights to scratch regardless of spelling. Pinning 1
//     wave/EU gives the full 256-VGPR budget (need ~180).
//   * cell state c lives in a register (same thread owns (l,n) forever).

#define HH    65
#define G4    260
#define TT    4096
#define NB    50
#define BLOCK 256
#define DROWS 64

__device__ __forceinline__ float sigm(float x)  { return 1.0f / (1.0f + __expf(-x)); }
__device__ __forceinline__ float tanha(float x) { float e = __expf(2.0f * x); return 1.0f - 2.0f / (e + 1.0f); }

__global__ void __launch_bounds__(BLOCK)
__attribute__((amdgpu_waves_per_eu(1, 1)))
charrnn_rec(const float* __restrict__ x, const float* __restrict__ W,
            const float* __restrict__ U, const float* __restrict__ bv,
            float* __restrict__ out)
{
    __shared__ __align__(16) float s_hin[3][68];   // input to layer l this round (row0 = x(t)); [65..67]=0
    __shared__ __align__(16) float s_hrec[3][68];  // recurrent h per layer; [65..67]=0
    __shared__ float s_zW[3][G4];                  // hin-side partial pre-activations
    __shared__ float s_zU[3][G4];                  // hrec-side partials (cols 0..251)
    __shared__ float s_zUe[3][4][8];               // hrec-side partials, cols 252..259, 4 k-chunks

    const int bat = blockIdx.x;
    const int tid = threadIdx.x;
    const float* xb   = x   + (size_t)bat * TT * HH;
    float*       outb = out + (size_t)bat * TT * HH;

    for (int i = tid; i < 3 * 68; i += BLOCK) { (&s_hin[0][0])[i] = 0.0f; (&s_hrec[0][0])[i] = 0.0f; }

    // ---- main slots: 130 W-threads own W cols (t, t+130); 126 U-threads own U cols (u, u+126) ----
    const bool isW = (tid < 130);
    int cA, cB;
    const float* wsrc;
    float biasA, biasB;
    if (isW) { cA = tid;  cB = tid + 130; wsrc = W; biasA = bv[cA]; biasB = bv[cB]; }
    else     { const int u = tid - 130; cA = u; cB = u + 126; wsrc = U; biasA = 0.0f; biasB = 0.0f; }

    // two 65-float weight columns (padded to 68) in NAMED float4 registers
    float4 wA00, wA01, wA02, wA03, wA04, wA05, wA06, wA07,
           wA08, wA09, wA10, wA11, wA12, wA13, wA14, wA15, wA16;
    float4 wB00, wB01, wB02, wB03, wB04, wB05, wB06, wB07,
           wB08, wB09, wB10, wB11, wB12, wB13, wB14, wB15, wB16;
#define WINIT(v, k0, c)                                                       \
    do {                                                                      \
        v.x = wsrc[(k0 + 0) * G4 + (c)];                                      \
        v.y = ((k0) + 1 < HH) ? wsrc[((k0) + 1) * G4 + (c)] : 0.0f;           \
        v.z = ((k0) + 2 < HH) ? wsrc[((k0) + 2) * G4 + (c)] : 0.0f;           \
        v.w = ((k0) + 3 < HH) ? wsrc[((k0) + 3) * G4 + (c)] : 0.0f;           \
    } while (0)
    WINIT(wA00, 0, cA);  WINIT(wA01, 4, cA);  WINIT(wA02, 8, cA);  WINIT(wA03, 12, cA);
    WINIT(wA04, 16, cA); WINIT(wA05, 20, cA); WINIT(wA06, 24, cA); WINIT(wA07, 28, cA);
    WINIT(wA08, 32, cA); WINIT(wA09, 36, cA); WINIT(wA10, 40, cA); WINIT(wA11, 44, cA);
    WINIT(wA12, 48, cA); WINIT(wA13, 52, cA); WINIT(wA14, 56, cA); WINIT(wA15, 60, cA);
    WINIT(wA16, 64, cA);
    WINIT(wB00, 0, cB);  WINIT(wB01, 4, cB);  WINIT(wB02, 8, cB);  WINIT(wB03, 12, cB);
    WINIT(wB04, 16, cB); WINIT(wB05, 20, cB); WINIT(wB06, 24, cB); WINIT(wB07, 28, cB);
    WINIT(wB08, 32, cB); WINIT(wB09, 36, cB); WINIT(wB10, 40, cB); WINIT(wB11, 44, cB);
    WINIT(wB12, 48, cB); WINIT(wB13, 52, cB); WINIT(wB14, 56, cB); WINIT(wB15, 60, cB);
    WINIT(wB16, 64, cB);
#undef WINIT

    // ---- leftover U cols 252..259, k-split x4: tid 192..223 -> chunk q = idx>>3, col 252+(idx&7) ----
    const bool isL  = (tid >= 192 && tid < 224);
    const int  idx  = tid - 192;
    const int  q    = idx >> 3;
    const int  lc   = idx & 7;
    const int  kst  = q * 17;
    const int  kln  = (q == 3) ? 14 : 17;
    float e00, e01, e02, e03, e04, e05, e06, e07, e08,
          e09, e10, e11, e12, e13, e14, e15, e16;
#define EINIT(i, v) v = (isL && (i) < kln) ? U[(kst + (i)) * G4 + (252 + lc)] : 0.0f
    EINIT(0, e00);  EINIT(1, e01);  EINIT(2, e02);  EINIT(3, e03);
    EINIT(4, e04);  EINIT(5, e05);  EINIT(6, e06);  EINIT(7, e07);
    EINIT(8, e08);  EINIT(9, e09);  EINIT(10, e10); EINIT(11, e11);
    EINIT(12, e12); EINIT(13, e13); EINIT(14, e14); EINIT(15, e15);
    EINIT(16, e16);
#undef EINIT

    // ---- x prefetch role: tid 191..255 -> element pidx = tid-191 (0..64) ----
    const bool isP  = (tid >= 191);
    const int  pidx = tid - 191;
    float cur = 0.0f, nxt = 0.0f;
    if (isP) {
        s_hin[0][pidx] = xb[pidx];      // x(0)
        cur = xb[HH + pidx];            // x(1)
    }

    float creg = 0.0f;                  // cell state for cell threads (tid<195)
    __syncthreads();

    for (int r = 0; r < TT + 2; ++r) {
        // ---------------- Phase A: gate partial dot-products ----------------
#pragma unroll
        for (int l = 0; l < 3; ++l) {
            if ((unsigned)(r - l) < TT) {
                const float* sb = isW ? &s_hin[l][0] : &s_hrec[l][0];
                const float4* s4 = (const float4*)sb;
                float aA0 = biasA, aA1 = 0.0f, aB0 = biasB, aB1 = 0.0f;
#define GSTEP(i, wa, wb)                                                      \
    {                                                                         \
        const float4 hv = s4[i];                                              \
        aA0 = fmaf(hv.x, wa.x, aA0); aB0 = fmaf(hv.x, wb.x, aB0);             \
        aA1 = fmaf(hv.y, wa.y, aA1); aB1 = fmaf(hv.y, wb.y, aB1);             \
        aA0 = fmaf(hv.z, wa.z, aA0); aB0 = fmaf(hv.z, wb.z, aB0);             \
        aA1 = fmaf(hv.w, wa.w, aA1); aB1 = fmaf(hv.w, wb.w, aB1);             \
    }
                GSTEP(0,  wA00, wB00) GSTEP(1,  wA01, wB01) GSTEP(2,  wA02, wB02)
                GSTEP(3,  wA03, wB03) GSTEP(4,  wA04, wB04) GSTEP(5,  wA05, wB05)
                GSTEP(6,  wA06, wB06) GSTEP(7,  wA07, wB07) GSTEP(8,  wA08, wB08)
                GSTEP(9,  wA09, wB09) GSTEP(10, wA10, wB10) GSTEP(11, wA11, wB11)
                GSTEP(12, wA12, wB12) GSTEP(13, wA13, wB13) GSTEP(14, wA14, wB14)
                GSTEP(15, wA15, wB15) GSTEP(16, wA16, wB16)
#undef GSTEP
                if (isW) { s_zW[l][cA] = aA0 + aA1; s_zW[l][cB] = aB0 + aB1; }
                else     { s_zU[l][cA] = aA0 + aA1; s_zU[l][cB] = aB0 + aB1; }
            }
        }
        if (isL) {
#pragma unroll
            for (int l = 0; l < 3; ++l) {
                if ((unsigned)(r - l) < TT) {
                    const float* hr = &s_hrec[l][0];   // [65..67] pad = 0, e1x = 0 past kln
                    float a = 0.0f;
                    a = fmaf(hr[kst + 0],  e00, a); a = fmaf(hr[kst + 1],  e01, a);
                    a = fmaf(hr[kst + 2],  e02, a); a = fmaf(hr[kst + 3],  e03, a);
                    a = fmaf(hr[kst + 4],  e04, a); a = fmaf(hr[kst + 5],  e05, a);
                    a = fmaf(hr[kst + 6],  e06, a); a = fmaf(hr[kst + 7],  e07, a);
                    a = fmaf(hr[kst + 8],  e08, a); a = fmaf(hr[kst + 9],  e09, a);
                    a = fmaf(hr[kst + 10], e10, a); a = fmaf(hr[kst + 11], e11, a);
                    a = fmaf(hr[kst + 12], e12, a); a = fmaf(hr[kst + 13], e13, a);
                    a = fmaf(hr[kst + 14], e14, a); a = fmaf(hr[kst + 15], e15, a);
                    a = fmaf(hr[kst + 16], e16, a);
                    s_zUe[l][q][lc] = a;
                }
            }
        }
        if (isP) {  // issue x(r+2); latency hidden under gate FMAs
            const int tn = r + 2;
            nxt = (tn < TT) ? xb[(size_t)tn * HH + pidx] : 0.0f;
        }
        __syncthreads();

        // ---------------- Phase B: cell updates ----------------
        if (tid < 195) {
            const int cl = tid / 65, n = tid - cl * 65;
            const int t  = r - cl;
            if ((unsigned)t < TT) {
                const float zi = s_zW[cl][n]       + s_zU[cl][n];
                const float zf = s_zW[cl][65 + n]  + s_zU[cl][65 + n];
                const float zg = s_zW[cl][130 + n] + s_zU[cl][130 + n];
                float zo = s_zW[cl][195 + n];
                if (n < 57) {
                    zo += s_zU[cl][195 + n];
                } else {
                    zo += (s_zUe[cl][0][n - 57] + s_zUe[cl][1][n - 57])
                        + (s_zUe[cl][2][n - 57] + s_zUe[cl][3][n - 57]);
                }
                const float ig = sigm(zi), fg = sigm(zf), gg = tanha(zg), og = sigm(zo);
                creg = fmaf(fg, creg, ig * gg);
                const float h = og * tanha(creg);
                s_hrec[cl][n] = h;
                if (cl < 2) s_hin[cl + 1][n] = h;
                else        outb[(size_t)t * HH + n] = h;   // stream h2 to out
            }
        }
        if (isP) {
            if (r + 1 < TT) s_hin[0][pidx] = cur;
            cur = nxt;
        }
        __syncthreads();
    }
}

// ---- kernel 2: in-place dense head over d_out: y = h2 @ Wd + bd ----
__global__ void __launch_bounds__(256, 1)
dense_head(float* __restrict__ io, const float* __restrict__ Wd, const float* __restrict__ bd)
{
    __shared__ __align__(16) float s_h[DROWS][68];
    __shared__ float s_wd[HH][HH];
    __shared__ float s_bd[HH];

    const int tid = threadIdx.x;
    float* base = io + (size_t)blockIdx.x * DROWS * HH;

    for (int i = tid; i < DROWS * HH; i += 256) {
        const int row = i / HH, k = i - row * HH;
        s_h[row][k] = base[i];
    }
    for (int i = tid; i < HH * HH; i += 256) (&s_wd[0][0])[i] = Wd[i];
    if (tid < HH) s_bd[tid] = bd[tid];
    __syncthreads();

    for (int u = tid; u < DROWS * HH; u += 256) {
        const int row = u / HH, c = u - row * HH;
        const float4* hp = (const float4*)&s_h[row][0];
        float acc = s_bd[c];
#pragma unroll
        for (int k4 = 0; k4 < 16; ++k4) {
            const float4 hv = hp[k4];
            acc = fmaf(hv.x, s_wd[4 * k4 + 0][c], acc);
            acc = fmaf(hv.y, s_wd[4 * k4 + 1][c], acc);
            acc = fmaf(hv.z, s_wd[4 * k4 + 2][c], acc);
            acc = fmaf(hv.w, s_wd[4 * k4 + 3][c], acc);
        }
        acc = fmaf(s_h[row][64], s_wd[64][c], acc);
        base[u] = acc;   // safe: all reads come from LDS copies
    }
}

extern "C" void kernel_launch(void* const* d_in, const int* in_sizes, int n_in,
                              void* d_out, int out_size, void* d_ws, size_t ws_size,
                              hipStream_t stream)
{
    const float* x  = (const float*)d_in[0];
    const float* W  = (const float*)d_in[1];
    const float* U  = (const float*)d_in[2];
    const float* bv = (const float*)d_in[3];
    const float* Wd = (const float*)d_in[4];
    const float* bd = (const float*)d_in[5];
    float* out = (float*)d_out;

    hipLaunchKernelGGL(charrnn_rec, dim3(NB), dim3(BLOCK), 0, stream, x, W, U, bv, out);
    hipLaunchKernelGGL(dense_head, dim3(NB * TT / DROWS), dim3(256), 0, stream, out, Wd, bd);
}

// Round 6
// 12461.640 us; speedup vs baseline: 1.2272x; 1.0566x over previous
//
#include <hip/hip_runtime.h>

// CharRNN: 3-layer shared-weight LSTM (H=65) over T=4096, B=50, + dense head.
//
// Kernel 1 (recurrent): one workgroup per sequence, layers wavefront-pipelined
//   (round r: layer l does t=r-l). Thread owns TWO gate columns (W-side or
//   U-side) and computes them for ALL 3 layers.
//
// Round-6 change vs round-5: every weight register is passed through an empty
//   asm volatile("" : "+v"(x)) after init. R5 showed VGPR=132 < ~150 live
//   weights: the compiler was REMATERIALIZING weight loads inside the loop
//   (re-fetching from L1/L2 every round) instead of keeping them resident.
//   The asm redefines the value so it cannot be recomputed from memory.

#define HH    65
#define G4    260
#define TT    4096
#define NB    50
#define BLOCK 256
#define DROWS 64

#define KEEP4(v) asm volatile("" : "+v"(v.x), "+v"(v.y), "+v"(v.z), "+v"(v.w))
#define KEEP(s)  asm volatile("" : "+v"(s))

__device__ __forceinline__ float sigm(float x)  { return 1.0f / (1.0f + __expf(-x)); }
__device__ __forceinline__ float tanha(float x) { float e = __expf(2.0f * x); return 1.0f - 2.0f / (e + 1.0f); }

__global__ void __launch_bounds__(BLOCK)
__attribute__((amdgpu_waves_per_eu(1, 1)))
charrnn_rec(const float* __restrict__ x, const float* __restrict__ W,
            const float* __restrict__ U, const float* __restrict__ bv,
            float* __restrict__ out)
{
    __shared__ __align__(16) float s_hin[3][68];   // input to layer l this round (row0 = x(t)); [65..67]=0
    __shared__ __align__(16) float s_hrec[3][68];  // recurrent h per layer; [65..67]=0
    __shared__ float s_zW[3][G4];                  // hin-side partial pre-activations
    __shared__ float s_zU[3][G4];                  // hrec-side partials (cols 0..251)
    __shared__ float s_zUe[3][4][8];               // hrec-side partials, cols 252..259, 4 k-chunks

    const int bat = blockIdx.x;
    const int tid = threadIdx.x;
    const float* xb   = x   + (size_t)bat * TT * HH;
    float*       outb = out + (size_t)bat * TT * HH;

    for (int i = tid; i < 3 * 68; i += BLOCK) { (&s_hin[0][0])[i] = 0.0f; (&s_hrec[0][0])[i] = 0.0f; }

    // ---- main slots: 130 W-threads own W cols (t, t+130); 126 U-threads own U cols (u, u+126) ----
    const bool isW = (tid < 130);
    int cA, cB;
    const float* wsrc;
    float biasA, biasB;
    if (isW) { cA = tid;  cB = tid + 130; wsrc = W; biasA = bv[cA]; biasB = bv[cB]; }
    else     { const int u = tid - 130; cA = u; cB = u + 126; wsrc = U; biasA = 0.0f; biasB = 0.0f; }
    KEEP(biasA); KEEP(biasB);

    // two 65-float weight columns (padded to 68) in NAMED float4 registers,
    // pinned against rematerialization via KEEP4.
    float4 wA00, wA01, wA02, wA03, wA04, wA05, wA06, wA07,
           wA08, wA09, wA10, wA11, wA12, wA13, wA14, wA15, wA16;
    float4 wB00, wB01, wB02, wB03, wB04, wB05, wB06, wB07,
           wB08, wB09, wB10, wB11, wB12, wB13, wB14, wB15, wB16;
#define WINIT(v, k0, c)                                                       \
    do {                                                                      \
        v.x = wsrc[(k0 + 0) * G4 + (c)];                                      \
        v.y = ((k0) + 1 < HH) ? wsrc[((k0) + 1) * G4 + (c)] : 0.0f;           \
        v.z = ((k0) + 2 < HH) ? wsrc[((k0) + 2) * G4 + (c)] : 0.0f;           \
        v.w = ((k0) + 3 < HH) ? wsrc[((k0) + 3) * G4 + (c)] : 0.0f;           \
        KEEP4(v);                                                             \
    } while (0)
    WINIT(wA00, 0, cA);  WINIT(wA01, 4, cA);  WINIT(wA02, 8, cA);  WINIT(wA03, 12, cA);
    WINIT(wA04, 16, cA); WINIT(wA05, 20, cA); WINIT(wA06, 24, cA); WINIT(wA07, 28, cA);
    WINIT(wA08, 32, cA); WINIT(wA09, 36, cA); WINIT(wA10, 40, cA); WINIT(wA11, 44, cA);
    WINIT(wA12, 48, cA); WINIT(wA13, 52, cA); WINIT(wA14, 56, cA); WINIT(wA15, 60, cA);
    WINIT(wA16, 64, cA);
    WINIT(wB00, 0, cB);  WINIT(wB01, 4, cB);  WINIT(wB02, 8, cB);  WINIT(wB03, 12, cB);
    WINIT(wB04, 16, cB); WINIT(wB05, 20, cB); WINIT(wB06, 24, cB); WINIT(wB07, 28, cB);
    WINIT(wB08, 32, cB); WINIT(wB09, 36, cB); WINIT(wB10, 40, cB); WINIT(wB11, 44, cB);
    WINIT(wB12, 48, cB); WINIT(wB13, 52, cB); WINIT(wB14, 56, cB); WINIT(wB15, 60, cB);
    WINIT(wB16, 64, cB);
#undef WINIT

    // ---- leftover U cols 252..259, k-split x4: tid 192..223 -> chunk q = idx>>3, col 252+(idx&7) ----
    const bool isL  = (tid >= 192 && tid < 224);
    const int  idx  = tid - 192;
    const int  q    = idx >> 3;
    const int  lc   = idx & 7;
    const int  kst  = q * 17;
    const int  kln  = (q == 3) ? 14 : 17;
    float e00, e01, e02, e03, e04, e05, e06, e07, e08,
          e09, e10, e11, e12, e13, e14, e15, e16;
#define EINIT(i, v)                                                           \
    do { v = (isL && (i) < kln) ? U[(kst + (i)) * G4 + (252 + lc)] : 0.0f;    \
         KEEP(v); } while (0)
    EINIT(0, e00);  EINIT(1, e01);  EINIT(2, e02);  EINIT(3, e03);
    EINIT(4, e04);  EINIT(5, e05);  EINIT(6, e06);  EINIT(7, e07);
    EINIT(8, e08);  EINIT(9, e09);  EINIT(10, e10); EINIT(11, e11);
    EINIT(12, e12); EINIT(13, e13); EINIT(14, e14); EINIT(15, e15);
    EINIT(16, e16);
#undef EINIT

    // ---- x prefetch role: tid 191..255 -> element pidx = tid-191 (0..64) ----
    const bool isP  = (tid >= 191);
    const int  pidx = tid - 191;
    float cur = 0.0f, nxt = 0.0f;
    if (isP) {
        s_hin[0][pidx] = xb[pidx];      // x(0)
        cur = xb[HH + pidx];            // x(1)
    }

    float creg = 0.0f;                  // cell state for cell threads (tid<195)
    __syncthreads();

    for (int r = 0; r < TT + 2; ++r) {
        // ---------------- Phase A: gate partial dot-products ----------------
#pragma unroll
        for (int l = 0; l < 3; ++l) {
            if ((unsigned)(r - l) < TT) {
                const float* sb = isW ? &s_hin[l][0] : &s_hrec[l][0];
                const float4* s4 = (const float4*)sb;
                float aA0 = biasA, aA1 = 0.0f, aB0 = biasB, aB1 = 0.0f;
#define GSTEP(i, wa, wb)                                                      \
    {                                                                         \
        const float4 hv = s4[i];                                              \
        aA0 = fmaf(hv.x, wa.x, aA0); aB0 = fmaf(hv.x, wb.x, aB0);             \
        aA1 = fmaf(hv.y, wa.y, aA1); aB1 = fmaf(hv.y, wb.y, aB1);             \
        aA0 = fmaf(hv.z, wa.z, aA0); aB0 = fmaf(hv.z, wb.z, aB0);             \
        aA1 = fmaf(hv.w, wa.w, aA1); aB1 = fmaf(hv.w, wb.w, aB1);             \
    }
                GSTEP(0,  wA00, wB00) GSTEP(1,  wA01, wB01) GSTEP(2,  wA02, wB02)
                GSTEP(3,  wA03, wB03) GSTEP(4,  wA04, wB04) GSTEP(5,  wA05, wB05)
                GSTEP(6,  wA06, wB06) GSTEP(7,  wA07, wB07) GSTEP(8,  wA08, wB08)
                GSTEP(9,  wA09, wB09) GSTEP(10, wA10, wB10) GSTEP(11, wA11, wB11)
                GSTEP(12, wA12, wB12) GSTEP(13, wA13, wB13) GSTEP(14, wA14, wB14)
                GSTEP(15, wA15, wB15) GSTEP(16, wA16, wB16)
#undef GSTEP
                if (isW) { s_zW[l][cA] = aA0 + aA1; s_zW[l][cB] = aB0 + aB1; }
                else     { s_zU[l][cA] = aA0 + aA1; s_zU[l][cB] = aB0 + aB1; }
            }
        }
        if (isL) {
#pragma unroll
            for (int l = 0; l < 3; ++l) {
                if ((unsigned)(r - l) < TT) {
                    const float* hr = &s_hrec[l][0];   // [65..67] pad = 0, e1x = 0 past kln
                    float a = 0.0f;
                    a = fmaf(hr[kst + 0],  e00, a); a = fmaf(hr[kst + 1],  e01, a);
                    a = fmaf(hr[kst + 2],  e02, a); a = fmaf(hr[kst + 3],  e03, a);
                    a = fmaf(hr[kst + 4],  e04, a); a = fmaf(hr[kst + 5],  e05, a);
                    a = fmaf(hr[kst + 6],  e06, a); a = fmaf(hr[kst + 7],  e07, a);
                    a = fmaf(hr[kst + 8],  e08, a); a = fmaf(hr[kst + 9],  e09, a);
                    a = fmaf(hr[kst + 10], e10, a); a = fmaf(hr[kst + 11], e11, a);
                    a = fmaf(hr[kst + 12], e12, a); a = fmaf(hr[kst + 13], e13, a);
                    a = fmaf(hr[kst + 14], e14, a); a = fmaf(hr[kst + 15], e15, a);
                    a = fmaf(hr[kst + 16], e16, a);
                    s_zUe[l][q][lc] = a;
                }
            }
        }
        if (isP) {  // issue x(r+2); latency hidden under gate FMAs
            const int tn = r + 2;
            nxt = (tn < TT) ? xb[(size_t)tn * HH + pidx] : 0.0f;
        }
        __syncthreads();

        // ---------------- Phase B: cell updates ----------------
        if (tid < 195) {
            const int cl = tid / 65, n = tid - cl * 65;
            const int t  = r - cl;
            if ((unsigned)t < TT) {
                const float zi = s_zW[cl][n]       + s_zU[cl][n];
                const float zf = s_zW[cl][65 + n]  + s_zU[cl][65 + n];
                const float zg = s_zW[cl][130 + n] + s_zU[cl][130 + n];
                float zo = s_zW[cl][195 + n];
                if (n < 57) {
                    zo += s_zU[cl][195 + n];
                } else {
                    zo += (s_zUe[cl][0][n - 57] + s_zUe[cl][1][n - 57])
                        + (s_zUe[cl][2][n - 57] + s_zUe[cl][3][n - 57]);
                }
                const float ig = sigm(zi), fg = sigm(zf), gg = tanha(zg), og = sigm(zo);
                creg = fmaf(fg, creg, ig * gg);
                const float h = og * tanha(creg);
                s_hrec[cl][n] = h;
                if (cl < 2) s_hin[cl + 1][n] = h;
                else        outb[(size_t)t * HH + n] = h;   // stream h2 to out
            }
        }
        if (isP) {
            if (r + 1 < TT) s_hin[0][pidx] = cur;
            cur = nxt;
        }
        __syncthreads();
    }
}

// ---- kernel 2: in-place dense head over d_out: y = h2 @ Wd + bd ----
__global__ void __launch_bounds__(256, 1)
dense_head(float* __restrict__ io, const float* __restrict__ Wd, const float* __restrict__ bd)
{
    __shared__ __align__(16) float s_h[DROWS][68];
    __shared__ float s_wd[HH][HH];
    __shared__ float s_bd[HH];

    const int tid = threadIdx.x;
    float* base = io + (size_t)blockIdx.x * DROWS * HH;

    for (int i = tid; i < DROWS * HH; i += 256) {
        const int row = i / HH, k = i - row * HH;
        s_h[row][k] = base[i];
    }
    for (int i = tid; i < HH * HH; i += 256) (&s_wd[0][0])[i] = Wd[i];
    if (tid < HH) s_bd[tid] = bd[tid];
    __syncthreads();

    for (int u = tid; u < DROWS * HH; u += 256) {
        const int row = u / HH, c = u - row * HH;
        const float4* hp = (const float4*)&s_h[row][0];
        float acc = s_bd[c];
#pragma unroll
        for (int k4 = 0; k4 < 16; ++k4) {
            const float4 hv = hp[k4];
            acc = fmaf(hv.x, s_wd[4 * k4 + 0][c], acc);
            acc = fmaf(hv.y, s_wd[4 * k4 + 1][c], acc);
            acc = fmaf(hv.z, s_wd[4 * k4 + 2][c], acc);
            acc = fmaf(hv.w, s_wd[4 * k4 + 3][c], acc);
        }
        acc = fmaf(s_h[row][64], s_wd[64][c], acc);
        base[u] = acc;   // safe: all reads come from LDS copies
    }
}

extern "C" void kernel_launch(void* const* d_in, const int* in_sizes, int n_in,
                              void* d_out, int out_size, void* d_ws, size_t ws_size,
                              hipStream_t stream)
{
    const float* x  = (const float*)d_in[0];
    const float* W  = (const float*)d_in[1];
    const float* U  = (const float*)d_in[2];
    const float* bv = (const float*)d_in[3];
    const float* Wd = (const float*)d_in[4];
    const float* bd = (const float*)d_in[5];
    float* out = (float*)d_out;

    hipLaunchKernelGGL(charrnn_rec, dim3(NB), dim3(BLOCK), 0, stream, x, W, U, bv, out);
    hipLaunchKernelGGL(dense_head, dim3(NB * TT / DROWS), dim3(256), 0, stream, out, Wd, bd);
}

// Round 7
// 11207.858 us; speedup vs baseline: 1.3644x; 1.1119x over previous
//
#include <hip/hip_runtime.h>

// CharRNN: 3-layer shared-weight LSTM (H=65) over T=4096, B=50, + dense head.
//
// Kernel 1 (recurrent): one workgroup per sequence, layers wavefront-pipelined
//   (round r: layer l does t=r-l). Thread owns ONE gate column (W-side or
//   U-side, 65 weights in named float4 regs) for ALL 3 layers.
//
// Round-7 theory: 50 blocks on 256 CUs = 1 block/CU always, so a 256-thread
// block ran at 1 wave/EU — ZERO latency hiding, and the allocator (132 VGPR)
// couldn't hold 136 weights. This round: 512 threads (8 waves = 2 waves/EU
// PHYSICAL -> TLP hides ds_read/scratch latency) + amdgpu_waves_per_eu(2,2)
// (VGPR budget 512/2 = 256; need ~165 for 68 wgt + 68 staged h + temps).
// h-loads are explicitly staged (17x float4, one lgkm wait) before 136 FMAs.

#define HH    65
#define G4    260
#define TT    4096
#define NB    50
#define BLOCK 512
#define DROWS 64

#define KEEP4(v) asm volatile("" : "+v"(v.x), "+v"(v.y), "+v"(v.z), "+v"(v.w))
#define KEEP(s)  asm volatile("" : "+v"(s))

__device__ __forceinline__ float sigm(float x)  { return 1.0f / (1.0f + __expf(-x)); }
__device__ __forceinline__ float tanha(float x) { float e = __expf(2.0f * x); return 1.0f - 2.0f / (e + 1.0f); }

__global__ void __launch_bounds__(BLOCK)
__attribute__((amdgpu_waves_per_eu(2, 2)))
charrnn_rec(const float* __restrict__ x, const float* __restrict__ W,
            const float* __restrict__ U, const float* __restrict__ bv,
            float* __restrict__ out)
{
    __shared__ __align__(16) float s_hin[3][68];   // input to layer l this round (row0 = x(t)); [65..67]=0
    __shared__ __align__(16) float s_hrec[3][68];  // recurrent h per layer; [65..67]=0
    __shared__ float s_zW[3][G4];                  // hin-side partial pre-activations
    __shared__ float s_zU[3][G4];                  // hrec-side partials (cols 0..251)
    __shared__ float s_zUe[3][8][8];               // hrec-side partials, cols 252..259, 8 k-chunks

    const int bat  = blockIdx.x;
    const int tid  = threadIdx.x;
    const int lane = tid & 63;
    const int wv   = tid >> 6;
    const float* xb   = x   + (size_t)bat * TT * HH;
    float*       outb = out + (size_t)bat * TT * HH;

    for (int i = tid; i < 3 * 68; i += BLOCK) { (&s_hin[0][0])[i] = 0.0f; (&s_hrec[0][0])[i] = 0.0f; }

    // ---- main slot: W-column (tid<260) or U-column (260<=tid<512 -> cols 0..251) ----
    const bool isW = (tid < G4);
    const int  col = isW ? tid : tid - G4;
    const float* wsrc = isW ? W : U;
    float bias = isW ? bv[col] : 0.0f;
    KEEP(bias);

    // one 65-float weight column (padded to 68) in NAMED float4 registers
    float4 w00, w01, w02, w03, w04, w05, w06, w07,
           w08, w09, w10, w11, w12, w13, w14, w15, w16;
#define WINIT(v, k0)                                                          \
    do {                                                                      \
        v.x = wsrc[(k0 + 0) * G4 + col];                                      \
        v.y = ((k0) + 1 < HH) ? wsrc[((k0) + 1) * G4 + col] : 0.0f;           \
        v.z = ((k0) + 2 < HH) ? wsrc[((k0) + 2) * G4 + col] : 0.0f;           \
        v.w = ((k0) + 3 < HH) ? wsrc[((k0) + 3) * G4 + col] : 0.0f;           \
        KEEP4(v);                                                             \
    } while (0)
    WINIT(w00, 0);  WINIT(w01, 4);  WINIT(w02, 8);  WINIT(w03, 12);
    WINIT(w04, 16); WINIT(w05, 20); WINIT(w06, 24); WINIT(w07, 28);
    WINIT(w08, 32); WINIT(w09, 36); WINIT(w10, 40); WINIT(w11, 44);
    WINIT(w12, 48); WINIT(w13, 52); WINIT(w14, 56); WINIT(w15, 60);
    WINIT(w16, 64);
#undef WINIT

    // ---- leftover U-columns 252..259: lanes 56..63 of each wave, k-chunk per wave ----
    const bool isL = (lane >= 56);
    const int  lc  = lane - 56;                        // col 252+lc
    const int  kst = (wv == 0) ? 0 : (9 + 8 * (wv - 1));
    const int  kln = (wv == 0) ? 9 : 8;
    float e0, e1, e2, e3, e4, e5, e6, e7, e8;
#define EINIT(i, v)                                                           \
    do { v = (isL && (i) < kln) ? U[(kst + (i)) * G4 + (252 + lc)] : 0.0f;    \
         KEEP(v); } while (0)
    EINIT(0, e0); EINIT(1, e1); EINIT(2, e2); EINIT(3, e3); EINIT(4, e4);
    EINIT(5, e5); EINIT(6, e6); EINIT(7, e7); EINIT(8, e8);
#undef EINIT

    // ---- x prefetch role: lanes 40..47 of each wave + tid 48 -> 65 elements ----
    const bool isP  = (lane >= 40 && lane < 48) || (tid == 48);
    const int  pidx = (tid == 48) ? 64 : (wv * 8 + (lane - 40));
    float cur = 0.0f, nxt = 0.0f;
    if (isP) {
        s_hin[0][pidx] = xb[pidx];      // x(0)
        cur = xb[HH + pidx];            // x(1)
    }

    float creg = 0.0f;                  // cell state for cell threads (tid<195)
    __syncthreads();

    for (int r = 0; r < TT + 2; ++r) {
        // ---------------- Phase A: gate partial dot-products ----------------
#pragma unroll
        for (int l = 0; l < 3; ++l) {
            if ((unsigned)(r - l) < TT) {
                const float4* s4 = (const float4*)(isW ? &s_hin[l][0] : &s_hrec[l][0]);
                // stage ALL h-loads first (one batched lgkm wait), then FMA
                const float4 h00 = s4[0],  h01 = s4[1],  h02 = s4[2],  h03 = s4[3];
                const float4 h04 = s4[4],  h05 = s4[5],  h06 = s4[6],  h07 = s4[7];
                const float4 h08 = s4[8],  h09 = s4[9],  h10 = s4[10], h11 = s4[11];
                const float4 h12 = s4[12], h13 = s4[13], h14 = s4[14], h15 = s4[15];
                const float4 h16 = s4[16];
                float a0 = bias, a1 = 0.0f, a2 = 0.0f, a3 = 0.0f;
#define GSTEP(hv, wv4)                                                        \
    {                                                                         \
        a0 = fmaf(hv.x, wv4.x, a0); a1 = fmaf(hv.y, wv4.y, a1);               \
        a2 = fmaf(hv.z, wv4.z, a2); a3 = fmaf(hv.w, wv4.w, a3);               \
    }
                GSTEP(h00, w00) GSTEP(h01, w01) GSTEP(h02, w02) GSTEP(h03, w03)
                GSTEP(h04, w04) GSTEP(h05, w05) GSTEP(h06, w06) GSTEP(h07, w07)
                GSTEP(h08, w08) GSTEP(h09, w09) GSTEP(h10, w10) GSTEP(h11, w11)
                GSTEP(h12, w12) GSTEP(h13, w13) GSTEP(h14, w14) GSTEP(h15, w15)
                GSTEP(h16, w16)
#undef GSTEP
                const float a = (a0 + a1) + (a2 + a3);
                if (isW) s_zW[l][col] = a; else s_zU[l][col] = a;
            }
        }
        if (isL) {
#pragma unroll
            for (int l = 0; l < 3; ++l) {
                if ((unsigned)(r - l) < TT) {
                    const float* hr = &s_hrec[l][0];   // [65..67] pad = 0; e8==0 for wv>0
                    float a = 0.0f;
                    a = fmaf(hr[kst + 0], e0, a); a = fmaf(hr[kst + 1], e1, a);
                    a = fmaf(hr[kst + 2], e2, a); a = fmaf(hr[kst + 3], e3, a);
                    a = fmaf(hr[kst + 4], e4, a); a = fmaf(hr[kst + 5], e5, a);
                    a = fmaf(hr[kst + 6], e6, a); a = fmaf(hr[kst + 7], e7, a);
                    a = fmaf(hr[kst + 8], e8, a);
                    s_zUe[l][wv][lc] = a;
                }
            }
        }
        if (isP) {  // issue x(r+2); latency hidden under gate FMAs
            const int tn = r + 2;
            nxt = (tn < TT) ? xb[(size_t)tn * HH + pidx] : 0.0f;
        }
        __syncthreads();

        // ---------------- Phase B: cell updates ----------------
        if (tid < 195) {
            const int cl = tid / 65, n = tid - cl * 65;
            const int t  = r - cl;
            if ((unsigned)t < TT) {
                const float zi = s_zW[cl][n]       + s_zU[cl][n];
                const float zf = s_zW[cl][65 + n]  + s_zU[cl][65 + n];
                const float zg = s_zW[cl][130 + n] + s_zU[cl][130 + n];
                float zo = s_zW[cl][195 + n];
                if (n < 57) {
                    zo += s_zU[cl][195 + n];
                } else {
                    const int m = n - 57;
                    zo += ((s_zUe[cl][0][m] + s_zUe[cl][1][m])
                         + (s_zUe[cl][2][m] + s_zUe[cl][3][m]))
                        + ((s_zUe[cl][4][m] + s_zUe[cl][5][m])
                         + (s_zUe[cl][6][m] + s_zUe[cl][7][m]));
                }
                const float ig = sigm(zi), fg = sigm(zf), gg = tanha(zg), og = sigm(zo);
                creg = fmaf(fg, creg, ig * gg);
                const float h = og * tanha(creg);
                s_hrec[cl][n] = h;
                if (cl < 2) s_hin[cl + 1][n] = h;
                else        outb[(size_t)t * HH + n] = h;   // stream h2 to out
            }
        }
        if (isP) {
            if (r + 1 < TT) s_hin[0][pidx] = cur;
            cur = nxt;
        }
        __syncthreads();
    }
}

// ---- kernel 2: in-place dense head over d_out: y = h2 @ Wd + bd ----
__global__ void __launch_bounds__(256, 1)
dense_head(float* __restrict__ io, const float* __restrict__ Wd, const float* __restrict__ bd)
{
    __shared__ __align__(16) float s_h[DROWS][68];
    __shared__ float s_wd[HH][HH];
    __shared__ float s_bd[HH];

    const int tid = threadIdx.x;
    float* base = io + (size_t)blockIdx.x * DROWS * HH;

    for (int i = tid; i < DROWS * HH; i += 256) {
        const int row = i / HH, k = i - row * HH;
        s_h[row][k] = base[i];
    }
    for (int i = tid; i < HH * HH; i += 256) (&s_wd[0][0])[i] = Wd[i];
    if (tid < HH) s_bd[tid] = bd[tid];
    __syncthreads();

    for (int u = tid; u < DROWS * HH; u += 256) {
        const int row = u / HH, c = u - row * HH;
        const float4* hp = (const float4*)&s_h[row][0];
        float acc = s_bd[c];
#pragma unroll
        for (int k4 = 0; k4 < 16; ++k4) {
            const float4 hv = hp[k4];
            acc = fmaf(hv.x, s_wd[4 * k4 + 0][c], acc);
            acc = fmaf(hv.y, s_wd[4 * k4 + 1][c], acc);
            acc = fmaf(hv.z, s_wd[4 * k4 + 2][c], acc);
            acc = fmaf(hv.w, s_wd[4 * k4 + 3][c], acc);
        }
        acc = fmaf(s_h[row][64], s_wd[64][c], acc);
        base[u] = acc;   // safe: all reads come from LDS copies
    }
}

extern "C" void kernel_launch(void* const* d_in, const int* in_sizes, int n_in,
                              void* d_out, int out_size, void* d_ws, size_t ws_size,
                              hipStream_t stream)
{
    const float* x  = (const float*)d_in[0];
    const float* W  = (const float*)d_in[1];
    const float* U  = (const float*)d_in[2];
    const float* bv = (const float*)d_in[3];
    const float* Wd = (const float*)d_in[4];
    const float* bd = (const float*)d_in[5];
    float* out = (float*)d_out;

    hipLaunchKernelGGL(charrnn_rec, dim3(NB), dim3(BLOCK), 0, stream, x, W, U, bv, out);
    hipLaunchKernelGGL(dense_head, dim3(NB * TT / DROWS), dim3(256), 0, stream, out, Wd, bd);
}

// Round 8
// 9931.881 us; speedup vs baseline: 1.5397x; 1.1285x over previous
//
#include <hip/hip_runtime.h>

// CharRNN: 3-layer shared-weight LSTM (H=65) over T=4096, B=50, + dense head.
//
// Round-8 structure: K-SPLIT GEMV. Block=1024 (16 waves, 4/SIMD). Thread
// (s,c)=(tid>>8, tid&255) computes window s of gate column c:
//   s=0: W rows 0..31, s=1: W rows 32..64, s=2: U rows 0..31, s=3: U rows 32..64
// for ALL 3 layers (shared weights). Only 33 weight floats/thread -> live set
// ~85 regs, far under the 128-VGPR cap at 4 waves/SIMD: no spill, no AGPR
// shuffling (R1-R7: allocator never granted >132 arch VGPRs; overflow went to
// AGPRs, costing a v_accvgpr_read per weight use = the dominant VALU tax).
// Wave = constant s: h-stages are perfect 64-lane broadcasts; s_part[l][s][c]
// writes are stride-4B conflict-free. Cell threads sum the 4 partials.
// Cols 256..259: 16-way k-split on threads c=64s+d (d<16), one group per SIMD.

#define HH    65
#define G4    260
#define TT    4096
#define NB    50
#define BLOCK 1024
#define DROWS 64

#define KEEP4(v) asm volatile("" : "+v"(v.x), "+v"(v.y), "+v"(v.z), "+v"(v.w))
#define KEEP(s)  asm volatile("" : "+v"(s))

__device__ __forceinline__ float sigm(float x)  { return 1.0f / (1.0f + __expf(-x)); }
__device__ __forceinline__ float tanha(float x) { float e = __expf(2.0f * x); return 1.0f - 2.0f / (e + 1.0f); }

__global__ void __launch_bounds__(BLOCK)
__attribute__((amdgpu_waves_per_eu(4, 4)))
charrnn_rec(const float* __restrict__ x, const float* __restrict__ W,
            const float* __restrict__ U, const float* __restrict__ bv,
            float* __restrict__ out)
{
    __shared__ __align__(16) float s_hin[3][68];   // input to layer l this round (row0 = x(t))
    __shared__ __align__(16) float s_hrec[3][68];  // recurrent h per layer
    __shared__ float s_part[3][4][256];            // [layer][window s][col] partial dots
    __shared__ float s_parte[3][4][16];            // [layer][col-256][window d] leftover partials
    __shared__ float s_bias[G4];

    const int bat = blockIdx.x;
    const int tid = threadIdx.x;
    const float* xb   = x   + (size_t)bat * TT * HH;
    float*       outb = out + (size_t)bat * TT * HH;

    for (int i = tid; i < 3 * 68; i += BLOCK) { (&s_hin[0][0])[i] = 0.0f; (&s_hrec[0][0])[i] = 0.0f; }
    if (tid < G4) s_bias[tid] = bv[tid];

    const int  s    = tid >> 8;        // 0..3 window
    const int  c    = tid & 255;       // 0..255 column
    const int  side = s >> 1;          // 0 = W/hin, 1 = U/hrec
    const int  k0   = (s & 1) * 32;    // rows k0..k0+31 (+64 if odd)
    const bool odd  = (s & 1) != 0;

    const float* wsrc = side ? U : W;
    float4 w0, w1, w2, w3, w4, w5, w6, w7;
    float  ws;
#define WINIT(v, kk)                                                          \
    do {                                                                      \
        v.x = wsrc[(k0 + (kk) + 0) * G4 + c];                                 \
        v.y = wsrc[(k0 + (kk) + 1) * G4 + c];                                 \
        v.z = wsrc[(k0 + (kk) + 2) * G4 + c];                                 \
        v.w = wsrc[(k0 + (kk) + 3) * G4 + c];                                 \
        KEEP4(v);                                                             \
    } while (0)
    WINIT(w0, 0);  WINIT(w1, 4);  WINIT(w2, 8);  WINIT(w3, 12);
    WINIT(w4, 16); WINIT(w5, 20); WINIT(w6, 24); WINIT(w7, 28);
#undef WINIT
    ws = odd ? wsrc[64 * G4 + c] : 0.0f; KEEP(ws);

    // ---- leftover cols 256..259: thread (s, c=64s+d, d<16) does window d of col 256+s ----
    const int  d     = c - 64 * s;
    const bool isL   = (d >= 0) && (d < 16);
    const int  sideL = (d >> 3) & 1;          // d<8: W, d>=8: U
    const int  k0L   = (d & 7) * 8;           // rows k0L..k0L+7 (+64 if d&7==7)
    const bool nineL = ((d & 7) == 7);
    const float* lsrc = sideL ? U : W;
    const int  colL  = 256 + s;
    float le0, le1, le2, le3, le4, le5, le6, le7, le8;
#define EINIT(i, v)                                                           \
    do { v = isL ? lsrc[(k0L + (i)) * G4 + colL] : 0.0f; KEEP(v); } while (0)
    EINIT(0, le0); EINIT(1, le1); EINIT(2, le2); EINIT(3, le3);
    EINIT(4, le4); EINIT(5, le5); EINIT(6, le6); EINIT(7, le7);
#undef EINIT
    le8 = (isL && nineL) ? lsrc[64 * G4 + colL] : 0.0f; KEEP(le8);

    // ---- x prefetch role: tid 704..768 -> element pidx = tid-704 (0..64) ----
    const bool isP  = (tid >= 704) && (tid <= 768);
    const int  pidx = tid - 704;
    float cur = 0.0f, nxt = 0.0f;
    if (isP) {
        s_hin[0][pidx] = xb[pidx];      // x(0)
        cur = xb[HH + pidx];            // x(1)
    }

    float creg = 0.0f;                  // cell state (cell threads tid<195)
    __syncthreads();

    for (int r = 0; r < TT + 2; ++r) {
        // ---------------- Phase A ----------------
        if (isP) {  // issue x(r+2) early; latency hidden under gate FMAs
            const int tn = r + 2;
            nxt = (tn < TT) ? xb[(size_t)tn * HH + pidx] : 0.0f;
        }
#pragma unroll
        for (int l = 0; l < 3; ++l) {
            if ((unsigned)(r - l) < TT) {
                const float* hb = side ? &s_hrec[l][0] : &s_hin[l][0];
                const float4* h4 = (const float4*)(hb + k0);
                const float4 g0 = h4[0], g1 = h4[1], g2 = h4[2], g3 = h4[3];
                const float4 g4v = h4[4], g5 = h4[5], g6 = h4[6], g7 = h4[7];
                const float  gs = odd ? hb[64] : 0.0f;
                float a0 = 0.0f, a1 = 0.0f, a2 = 0.0f, a3 = 0.0f;
#define GS(gv, wv)                                                            \
    { a0 = fmaf(gv.x, wv.x, a0); a1 = fmaf(gv.y, wv.y, a1);                   \
      a2 = fmaf(gv.z, wv.z, a2); a3 = fmaf(gv.w, wv.w, a3); }
                GS(g0, w0) GS(g1, w1) GS(g2, w2) GS(g3, w3)
                GS(g4v, w4) GS(g5, w5) GS(g6, w6) GS(g7, w7)
#undef GS
                a0 = fmaf(gs, ws, a0);
                s_part[l][s][c] = (a0 + a1) + (a2 + a3);
            }
        }
        if (isL) {
#pragma unroll
            for (int l = 0; l < 3; ++l) {
                if ((unsigned)(r - l) < TT) {
                    const float* hb = sideL ? &s_hrec[l][0] : &s_hin[l][0];
                    const float4* h4 = (const float4*)(hb + k0L);
                    const float4 p0 = h4[0], p1 = h4[1];
                    float a = 0.0f, b2 = 0.0f;
                    a  = fmaf(p0.x, le0, a);  b2 = fmaf(p0.y, le1, b2);
                    a  = fmaf(p0.z, le2, a);  b2 = fmaf(p0.w, le3, b2);
                    a  = fmaf(p1.x, le4, a);  b2 = fmaf(p1.y, le5, b2);
                    a  = fmaf(p1.z, le6, a);  b2 = fmaf(p1.w, le7, b2);
                    if (nineL) a = fmaf(hb[64], le8, a);
                    s_parte[l][s][d] = a + b2;
                }
            }
        }
        __syncthreads();

        // ---------------- Phase B: cell updates ----------------
        if (tid < 195) {
            const int cl = tid / 65, n = tid - cl * 65;
            if ((unsigned)(r - cl) < TT) {
                const float zi = s_bias[n]
                    + ((s_part[cl][0][n]       + s_part[cl][1][n])
                     + (s_part[cl][2][n]       + s_part[cl][3][n]));
                const float zf = s_bias[65 + n]
                    + ((s_part[cl][0][65 + n]  + s_part[cl][1][65 + n])
                     + (s_part[cl][2][65 + n]  + s_part[cl][3][65 + n]));
                const float zg = s_bias[130 + n]
                    + ((s_part[cl][0][130 + n] + s_part[cl][1][130 + n])
                     + (s_part[cl][2][130 + n] + s_part[cl][3][130 + n]));
                float zo = s_bias[195 + n];
                if (n < 61) {
                    const int jo = 195 + n;
                    zo += ((s_part[cl][0][jo] + s_part[cl][1][jo])
                         + (s_part[cl][2][jo] + s_part[cl][3][jo]));
                } else {
                    const float* pe = &s_parte[cl][n - 61][0];
                    float t0 = 0.0f, t1 = 0.0f;
                    t0 += pe[0];  t1 += pe[1];  t0 += pe[2];  t1 += pe[3];
                    t0 += pe[4];  t1 += pe[5];  t0 += pe[6];  t1 += pe[7];
                    t0 += pe[8];  t1 += pe[9];  t0 += pe[10]; t1 += pe[11];
                    t0 += pe[12]; t1 += pe[13]; t0 += pe[14]; t1 += pe[15];
                    zo += t0 + t1;
                }
                const float ig = sigm(zi), fg = sigm(zf), gg = tanha(zg), og = sigm(zo);
                creg = fmaf(fg, creg, ig * gg);
                const float h = og * tanha(creg);
                s_hrec[cl][n] = h;
                if (cl < 2) s_hin[cl + 1][n] = h;
                else        outb[(size_t)(r - cl) * HH + n] = h;   // stream h2 to out
            }
        }
        if (isP) {
            if (r + 1 < TT) s_hin[0][pidx] = cur;
            cur = nxt;
        }
        __syncthreads();
    }
}

// ---- kernel 2: in-place dense head over d_out: y = h2 @ Wd + bd ----
__global__ void __launch_bounds__(256, 1)
dense_head(float* __restrict__ io, const float* __restrict__ Wd, const float* __restrict__ bd)
{
    __shared__ __align__(16) float s_h[DROWS][68];
    __shared__ float s_wd[HH][HH];
    __shared__ float s_bd[HH];

    const int tid = threadIdx.x;
    float* base = io + (size_t)blockIdx.x * DROWS * HH;

    for (int i = tid; i < DROWS * HH; i += 256) {
        const int row = i / HH, k = i - row * HH;
        s_h[row][k] = base[i];
    }
    for (int i = tid; i < HH * HH; i += 256) (&s_wd[0][0])[i] = Wd[i];
    if (tid < HH) s_bd[tid] = bd[tid];
    __syncthreads();

    for (int u = tid; u < DROWS * HH; u += 256) {
        const int row = u / HH, c = u - row * HH;
        const float4* hp = (const float4*)&s_h[row][0];
        float acc = s_bd[c];
#pragma unroll
        for (int k4 = 0; k4 < 16; ++k4) {
            const float4 hv = hp[k4];
            acc = fmaf(hv.x, s_wd[4 * k4 + 0][c], acc);
            acc = fmaf(hv.y, s_wd[4 * k4 + 1][c], acc);
            acc = fmaf(hv.z, s_wd[4 * k4 + 2][c], acc);
            acc = fmaf(hv.w, s_wd[4 * k4 + 3][c], acc);
        }
        acc = fmaf(s_h[row][64], s_wd[64][c], acc);
        base[u] = acc;   // safe: all reads come from LDS copies
    }
}

extern "C" void kernel_launch(void* const* d_in, const int* in_sizes, int n_in,
                              void* d_out, int out_size, void* d_ws, size_t ws_size,
                              hipStream_t stream)
{
    const float* x  = (const float*)d_in[0];
    const float* W  = (const float*)d_in[1];
    const float* U  = (const float*)d_in[2];
    const float* bv = (const float*)d_in[3];
    const float* Wd = (const float*)d_in[4];
    const float* bd = (const float*)d_in[5];
    float* out = (float*)d_out;

    hipLaunchKernelGGL(charrnn_rec, dim3(NB), dim3(BLOCK), 0, stream, x, W, U, bv, out);
    hipLaunchKernelGGL(dense_head, dim3(NB * TT / DROWS), dim3(256), 0, stream, out, Wd, bd);
}

// Round 9
// 6012.817 us; speedup vs baseline: 2.5433x; 1.6518x over previous
//
#include <hip/hip_runtime.h>

// CharRNN: 3-layer shared-weight LSTM (H=65) over T=4096, B=50, + dense head.
//
// Round-9: LDS-instruction minimization. R8 was LDS-pipe-bound: 384
// ds_read_b128/CU/round (x12cyc ~ 4.6K cyc) from every thread re-staging a
// 32-float h window. Now: thread = (side, col-quad, k-window) with C=4 cols
// x S=4 windows of 16 rows -> 4 aligned b128 (+1 broadcast b32) per layer,
// 120 staging instr/round. Window partials reduced IN-REGISTER via DPP
// quad_perm (no LDS); one masked ds_write_b128 per wave/layer publishes 4
// column dots. Phase B: 8 b32 reads + register bias per cell.
// Cols 256..259 (o-gate, cells 61..64) ride on lanes 0..15 of waves 0/4
// (same staged h), DPP-reduced into s_parte.

#define HH    65
#define G4    260
#define TT    4096
#define NB    50
#define BLOCK 512
#define DROWS 64

#define KEEP4(v) asm volatile("" : "+v"(v.x), "+v"(v.y), "+v"(v.z), "+v"(v.w))
#define KEEP(s)  asm volatile("" : "+v"(s))

__device__ __forceinline__ float sigm(float x)  { return 1.0f / (1.0f + __expf(-x)); }
__device__ __forceinline__ float tanha(float x) { float e = __expf(2.0f * x); return 1.0f - 2.0f / (e + 1.0f); }

// sum across the 4 lanes of a quad (lane bits 0-1) via DPP; all 4 lanes get total
__device__ __forceinline__ float qsum(float v) {
    int i = __float_as_int(v);
    v += __int_as_float(__builtin_amdgcn_update_dpp(0, i, 0xB1, 0xF, 0xF, true)); // quad_perm [1,0,3,2]
    i = __float_as_int(v);
    v += __int_as_float(__builtin_amdgcn_update_dpp(0, i, 0x4E, 0xF, 0xF, true)); // quad_perm [2,3,0,1]
    return v;
}

__global__ void __launch_bounds__(BLOCK)
__attribute__((amdgpu_waves_per_eu(2, 2)))
charrnn_rec(const float* __restrict__ x, const float* __restrict__ W,
            const float* __restrict__ U, const float* __restrict__ bv,
            float* __restrict__ out)
{
    __shared__ __align__(16) float s_hin[3][68];    // input to layer l (row0 = x(t)); [65..67]=0
    __shared__ __align__(16) float s_hrec[3][68];   // recurrent h per layer
    __shared__ __align__(16) float s_z[3][2][256];  // [layer][side][col] full dots, cols 0..255
    __shared__ float s_parte[3][2][4];              // [layer][side][col-256] dots, cols 256..259

    const int bat = blockIdx.x;
    const int tid = threadIdx.x;
    const float* xb   = x   + (size_t)bat * TT * HH;
    float*       outb = out + (size_t)bat * TT * HH;

    for (int i = tid; i < 3 * 68; i += BLOCK) { (&s_hin[0][0])[i] = 0.0f; (&s_hrec[0][0])[i] = 0.0f; }

    const int w    = tid & 3;             // k-window: rows 16w..16w+15 (+ row 64 on w==3)
    const int side = tid >> 8;            // 0 = W (reads hin), 1 = U (reads hrec)
    const int qL   = (tid >> 2) & 63;     // column quad within side
    const int col0 = qL * 4;              // cols col0..col0+3 (0..255)
    const float* M = side ? U : W;

    // 16 float4 weights: w{c}{q}.e = M[16w+4q+e][col0+c]; ws{c} = M[64][col0+c] (w==3 only)
    float4 wa0, wa1, wa2, wa3, wb0, wb1, wb2, wb3,
           wc0, wc1, wc2, wc3, wd0, wd1, wd2, wd3;
#define WLD(v, c, q)                                                          \
    do {                                                                      \
        v.x = M[(16 * w + 4 * (q) + 0) * G4 + col0 + (c)];                    \
        v.y = M[(16 * w + 4 * (q) + 1) * G4 + col0 + (c)];                    \
        v.z = M[(16 * w + 4 * (q) + 2) * G4 + col0 + (c)];                    \
        v.w = M[(16 * w + 4 * (q) + 3) * G4 + col0 + (c)];                    \
        KEEP4(v);                                                             \
    } while (0)
    WLD(wa0, 0, 0); WLD(wa1, 0, 1); WLD(wa2, 0, 2); WLD(wa3, 0, 3);
    WLD(wb0, 1, 0); WLD(wb1, 1, 1); WLD(wb2, 1, 2); WLD(wb3, 1, 3);
    WLD(wc0, 2, 0); WLD(wc1, 2, 1); WLD(wc2, 2, 2); WLD(wc3, 2, 3);
    WLD(wd0, 3, 0); WLD(wd1, 3, 1); WLD(wd2, 3, 2); WLD(wd3, 3, 3);
#undef WLD
    float ws0 = (w == 3) ? M[64 * G4 + col0 + 0] : 0.0f; KEEP(ws0);
    float ws1 = (w == 3) ? M[64 * G4 + col0 + 1] : 0.0f; KEEP(ws1);
    float ws2 = (w == 3) ? M[64 * G4 + col0 + 2] : 0.0f; KEEP(ws2);
    float ws3 = (w == 3) ? M[64 * G4 + col0 + 3] : 0.0f; KEEP(ws3);

    // extra cols 256..259: lanes 0..15 of waves 0 (W-side) and 4 (U-side)
    const bool isX  = ((tid & 255) < 16);
    const int  colX = 256 + ((tid >> 2) & 3);
    float4 e0, e1, e2, e3;
    float  esc;
#define ELD(v, q)                                                             \
    do {                                                                      \
        v.x = isX ? M[(16 * w + 4 * (q) + 0) * G4 + colX] : 0.0f;             \
        v.y = isX ? M[(16 * w + 4 * (q) + 1) * G4 + colX] : 0.0f;             \
        v.z = isX ? M[(16 * w + 4 * (q) + 2) * G4 + colX] : 0.0f;             \
        v.w = isX ? M[(16 * w + 4 * (q) + 3) * G4 + colX] : 0.0f;             \
        KEEP4(v);                                                             \
    } while (0)
    ELD(e0, 0); ELD(e1, 1); ELD(e2, 2); ELD(e3, 3);
#undef ELD
    esc = (isX && w == 3) ? M[64 * G4 + colX] : 0.0f; KEEP(esc);

    // cell role (tid < 195): biases pre-loaded to registers
    const int  cl = tid / 65, n = tid - (tid / 65) * 65;   // n in 0..64 for all tids
    const bool isC = (tid < 195);
    const float bz0 = bv[n], bz1 = bv[65 + n], bz2 = bv[130 + n], bz3 = bv[195 + n];
    float creg = 0.0f;

    // x prefetch: tids 447..511 -> pidx 0..64
    const bool isP  = (tid >= 447);
    const int  pidx = tid - 447;
    float cur = 0.0f, nxt = 0.0f;
    if (isP) {
        s_hin[0][pidx] = xb[pidx];      // x(0)
        cur = xb[HH + pidx];            // x(1)
    }
    __syncthreads();

    for (int r = 0; r < TT + 2; ++r) {
        // ---------------- Phase A ----------------
        if (isP) {  // issue x(r+2) early
            const int tn = r + 2;
            nxt = (tn < TT) ? xb[(size_t)tn * HH + pidx] : 0.0f;
        }
#pragma unroll
        for (int l = 0; l < 3; ++l) {
            if ((unsigned)(r - l) < TT) {
                const float* hb = side ? &s_hrec[l][0] : &s_hin[l][0];
                const float4* h4 = (const float4*)(hb + 16 * w);   // 16B aligned
                const float4 H0 = h4[0], H1 = h4[1], H2 = h4[2], H3 = h4[3];
                const float  h64 = hb[64];                          // broadcast b32
                float a0, a1, a2, a3;
#define COLDOT(acc, p0, p1, p2, p3, ps)                                       \
    {   float u0, u1;                                                         \
        u0 = H0.x * p0.x;           u1 = H0.y * p0.y;                         \
        u0 = fmaf(H0.z, p0.z, u0);  u1 = fmaf(H0.w, p0.w, u1);                \
        u0 = fmaf(H1.x, p1.x, u0);  u1 = fmaf(H1.y, p1.y, u1);                \
        u0 = fmaf(H1.z, p1.z, u0);  u1 = fmaf(H1.w, p1.w, u1);                \
        u0 = fmaf(H2.x, p2.x, u0);  u1 = fmaf(H2.y, p2.y, u1);                \
        u0 = fmaf(H2.z, p2.z, u0);  u1 = fmaf(H2.w, p2.w, u1);                \
        u0 = fmaf(H3.x, p3.x, u0);  u1 = fmaf(H3.y, p3.y, u1);                \
        u0 = fmaf(H3.z, p3.z, u0);  u1 = fmaf(H3.w, p3.w, u1);                \
        u0 = fmaf(h64, ps, u0);                                               \
        acc = u0 + u1; }
                COLDOT(a0, wa0, wa1, wa2, wa3, ws0)
                COLDOT(a1, wb0, wb1, wb2, wb3, ws1)
                COLDOT(a2, wc0, wc1, wc2, wc3, ws2)
                COLDOT(a3, wd0, wd1, wd2, wd3, ws3)
                a0 = qsum(a0); a1 = qsum(a1); a2 = qsum(a2); a3 = qsum(a3);
                if (w == 0)
                    *(float4*)&s_z[l][side][col0] = make_float4(a0, a1, a2, a3);
                if (isX) {
                    float ea;
                    COLDOT(ea, e0, e1, e2, e3, esc)
                    ea = qsum(ea);
                    if (w == 0) s_parte[l][side][(tid >> 2) & 3] = ea;
                }
#undef COLDOT
            }
        }
        __syncthreads();

        // ---------------- Phase B: cell updates ----------------
        if (isC) {
            if ((unsigned)(r - cl) < TT) {
                const float zi = bz0 + s_z[cl][0][n]       + s_z[cl][1][n];
                const float zf = bz1 + s_z[cl][0][65 + n]  + s_z[cl][1][65 + n];
                const float zg = bz2 + s_z[cl][0][130 + n] + s_z[cl][1][130 + n];
                float zo;
                if (n < 61) zo = bz3 + s_z[cl][0][195 + n]   + s_z[cl][1][195 + n];
                else        zo = bz3 + s_parte[cl][0][n - 61] + s_parte[cl][1][n - 61];
                const float ig = sigm(zi), fg = sigm(zf), gg = tanha(zg), og = sigm(zo);
                creg = fmaf(fg, creg, ig * gg);
                const float h = og * tanha(creg);
                s_hrec[cl][n] = h;
                if (cl < 2) s_hin[cl + 1][n] = h;
                else        outb[(size_t)(r - cl) * HH + n] = h;   // stream h2 to out
            }
        }
        if (isP) {
            if (r + 1 < TT) s_hin[0][pidx] = cur;
            cur = nxt;
        }
        __syncthreads();
    }
}

// ---- kernel 2: in-place dense head over d_out: y = h2 @ Wd + bd ----
__global__ void __launch_bounds__(256, 1)
dense_head(float* __restrict__ io, const float* __restrict__ Wd, const float* __restrict__ bd)
{
    __shared__ __align__(16) float s_h[DROWS][68];
    __shared__ float s_wd[HH][HH];
    __shared__ float s_bd[HH];

    const int tid = threadIdx.x;
    float* base = io + (size_t)blockIdx.x * DROWS * HH;

    for (int i = tid; i < DROWS * HH; i += 256) {
        const int row = i / HH, k = i - row * HH;
        s_h[row][k] = base[i];
    }
    for (int i = tid; i < HH * HH; i += 256) (&s_wd[0][0])[i] = Wd[i];
    if (tid < HH) s_bd[tid] = bd[tid];
    __syncthreads();

    for (int u = tid; u < DROWS * HH; u += 256) {
        const int row = u / HH, c = u - row * HH;
        const float4* hp = (const float4*)&s_h[row][0];
        float acc = s_bd[c];
#pragma unroll
        for (int k4 = 0; k4 < 16; ++k4) {
            const float4 hv = hp[k4];
            acc = fmaf(hv.x, s_wd[4 * k4 + 0][c], acc);
            acc = fmaf(hv.y, s_wd[4 * k4 + 1][c], acc);
            acc = fmaf(hv.z, s_wd[4 * k4 + 2][c], acc);
            acc = fmaf(hv.w, s_wd[4 * k4 + 3][c], acc);
        }
        acc = fmaf(s_h[row][64], s_wd[64][c], acc);
        base[u] = acc;   // safe: all reads come from LDS copies
    }
}

extern "C" void kernel_launch(void* const* d_in, const int* in_sizes, int n_in,
                              void* d_out, int out_size, void* d_ws, size_t ws_size,
                              hipStream_t stream)
{
    const float* x  = (const float*)d_in[0];
    const float* W  = (const float*)d_in[1];
    const float* U  = (const float*)d_in[2];
    const float* bv = (const float*)d_in[3];
    const float* Wd = (const float*)d_in[4];
    const float* bd = (const float*)d_in[5];
    float* out = (float*)d_out;

    hipLaunchKernelGGL(charrnn_rec, dim3(NB), dim3(BLOCK), 0, stream, x, W, U, bv, out);
    hipLaunchKernelGGL(dense_head, dim3(NB * TT / DROWS), dim3(256), 0, stream, out, Wd, bd);
}